// Round 1
// baseline (292.303 us; speedup 1.0000x reference)
//
#include <hip/hip_runtime.h>
#include <math.h>

#define N_NODES 50000
#define N_EDGES 800000
#define D 128
#define BN_EPS 1e-5f

// ---------------- octonion Hamilton tables ----------------
// _OCT_TABLE[j][i] = (component, sign): H[i*16+k][j*16+m] = s * W[k][c*16+m]
__device__ __constant__ int OCT_C[8][8] = {
    {0,1,2,3,4,5,6,7},
    {1,0,3,2,5,4,7,6},
    {2,3,0,1,6,7,4,5},
    {3,2,1,0,7,6,5,4},
    {4,5,6,7,0,1,2,3},
    {5,4,7,6,1,0,3,2},
    {6,7,4,5,2,3,0,1},
    {7,6,5,4,3,2,1,0}};
__device__ __constant__ float OCT_S[8][8] = {
    { 1,-1,-1,-1,-1,-1,-1,-1},
    { 1, 1,-1, 1,-1, 1, 1,-1},
    { 1, 1, 1,-1,-1,-1, 1, 1},
    { 1,-1, 1, 1,-1, 1,-1, 1},
    { 1, 1, 1, 1, 1,-1,-1,-1},
    { 1,-1, 1,-1, 1, 1, 1,-1},
    { 1,-1,-1, 1, 1,-1, 1, 1},
    { 1, 1,-1,-1, 1, 1,-1, 1}};

// ---------------- kernels ----------------

__global__ void zero_kernel(int* __restrict__ cnt, float* __restrict__ stats) {
    int i = blockIdx.x * 256 + threadIdx.x;
    if (i < N_NODES) cnt[i] = 0;
    if (i < 2 * D) stats[i] = 0.0f;
}

__global__ void build_h_kernel(const float* __restrict__ W, float* __restrict__ H) {
    int idx = blockIdx.x * 256 + threadIdx.x;   // 64 blocks * 256 = 16384
    int row = idx >> 7, col = idx & 127;
    int i = row >> 4, k = row & 15, j = col >> 4, m = col & 15;
    int c = OCT_C[j][i];
    float s = OCT_S[j][i];
    H[idx] = s * W[k * D + c * 16 + m];
}

__global__ void count_kernel(const int* __restrict__ arow, int* __restrict__ cnt) {
    int i = blockIdx.x * 256 + threadIdx.x;
    if (i < N_EDGES) atomicAdd(&cnt[arow[i]], 1);
}

// single-block exclusive scan of cnt[0..N_NODES) -> rowptr, rowcur
__global__ void scan_kernel(const int* __restrict__ cnt, int* __restrict__ rowptr,
                            int* __restrict__ rowcur) {
    const int tid = threadIdx.x;        // 1024 threads
    const int lane = tid & 63, wid = tid >> 6;  // 16 waves
    __shared__ int wtot[16];
    __shared__ int carry;
    if (tid == 0) carry = 0;
    __syncthreads();
    const int PER = 8;
    for (int start = 0; start < N_NODES; start += 1024 * PER) {
        int base_i = start + tid * PER;
        int v[PER];
        int s = 0;
#pragma unroll
        for (int j = 0; j < PER; ++j) {
            int i = base_i + j;
            v[j] = (i < N_NODES) ? cnt[i] : 0;
            s += v[j];
        }
        int incl = s;
#pragma unroll
        for (int off = 1; off < 64; off <<= 1) {
            int t = __shfl_up(incl, off, 64);
            if (lane >= off) incl += t;
        }
        if (lane == 63) wtot[wid] = incl;
        __syncthreads();
        if (tid == 0) {
            int acc = carry;
#pragma unroll
            for (int w = 0; w < 16; ++w) { int t = wtot[w]; wtot[w] = acc; acc += t; }
            carry = acc;
        }
        __syncthreads();
        int excl = wtot[wid] + (incl - s);
#pragma unroll
        for (int j = 0; j < PER; ++j) {
            int i = base_i + j;
            if (i < N_NODES) { rowptr[i] = excl; rowcur[i] = excl; }
            excl += v[j];
        }
        __syncthreads();
    }
    if (tid == 0) rowptr[N_NODES] = carry;
}

__global__ void scatter_kernel(const int* __restrict__ arow, const int* __restrict__ acol,
                               const float* __restrict__ aval, int* __restrict__ rowcur,
                               int* __restrict__ ecol, float* __restrict__ eval_) {
    int i = blockIdx.x * 256 + threadIdx.x;
    if (i < N_EDGES) {
        int r = arow[i];
        int pos = atomicAdd(&rowcur[r], 1);
        ecol[pos] = acol[i];
        eval_[pos] = aval[i];
    }
}

// support = input @ H ; H staged in LDS; 32 rows/block, thread = (rowgroup, colquad)
__global__ __launch_bounds__(256) void gemm_kernel(const float* __restrict__ in,
                                                   const float* __restrict__ H,
                                                   float* __restrict__ support) {
    __shared__ float Hs[D * D];       // 64 KB
    const int tid = threadIdx.x;
    for (int t = tid; t < D * D / 4; t += 256)
        reinterpret_cast<float4*>(Hs)[t] = reinterpret_cast<const float4*>(H)[t];
    __syncthreads();

    const int cq = tid & 31;          // column quad 0..31 -> cols cq*4..cq*4+3
    const int g  = tid >> 5;          // row group 0..7
    const int row0 = blockIdx.x * 32 + g;   // rows row0 + {0,8,16,24}

    const float* ip[4];
    int rows[4];
    float4 acc[4];
#pragma unroll
    for (int r = 0; r < 4; ++r) {
        rows[r] = row0 + r * 8;
        int lr = rows[r] < N_NODES ? rows[r] : N_NODES - 1;
        ip[r] = in + (size_t)lr * D;
        acc[r] = make_float4(0.f, 0.f, 0.f, 0.f);
    }

    for (int kk = 0; kk < D; kk += 4) {
        float4 a[4];
#pragma unroll
        for (int r = 0; r < 4; ++r)
            a[r] = *reinterpret_cast<const float4*>(ip[r] + kk);
#pragma unroll
        for (int j = 0; j < 4; ++j) {
            float4 h = *reinterpret_cast<const float4*>(&Hs[(kk + j) * D + cq * 4]);
#pragma unroll
            for (int r = 0; r < 4; ++r) {
                float aj = (j == 0) ? a[r].x : (j == 1) ? a[r].y : (j == 2) ? a[r].z : a[r].w;
                acc[r].x += aj * h.x;
                acc[r].y += aj * h.y;
                acc[r].z += aj * h.z;
                acc[r].w += aj * h.w;
            }
        }
    }
#pragma unroll
    for (int r = 0; r < 4; ++r)
        if (rows[r] < N_NODES)
            *reinterpret_cast<float4*>(support + (size_t)rows[r] * D + cq * 4) = acc[r];
}

// CSR spmm: 32-thread group per row, float4 per lane; fused BN column stats
__global__ __launch_bounds__(256) void spmm_kernel(const float* __restrict__ support,
                                                   const int* __restrict__ rowptr,
                                                   const int* __restrict__ ecol,
                                                   const float* __restrict__ eval_,
                                                   float* __restrict__ out,
                                                   float* __restrict__ colsum,
                                                   float* __restrict__ colsq) {
    const int tid = threadIdx.x;
    const int lane = tid & 31;        // col quad
    const int g = tid >> 5;           // 0..7 row groups
    const int c4 = lane * 4;

    float4 sum = make_float4(0.f, 0.f, 0.f, 0.f);
    float4 sq  = make_float4(0.f, 0.f, 0.f, 0.f);

    for (int row = blockIdx.x * 8 + g; row < N_NODES; row += gridDim.x * 8) {
        float4 acc = make_float4(0.f, 0.f, 0.f, 0.f);
        int e0 = rowptr[row], e1 = rowptr[row + 1];
        int e = e0;
        for (; e + 1 < e1; e += 2) {
            int   c0 = ecol[e],     c1 = ecol[e + 1];
            float v0 = eval_[e],    v1 = eval_[e + 1];
            float4 s0 = *reinterpret_cast<const float4*>(support + (size_t)c0 * D + c4);
            float4 s1 = *reinterpret_cast<const float4*>(support + (size_t)c1 * D + c4);
            acc.x += v0 * s0.x; acc.y += v0 * s0.y; acc.z += v0 * s0.z; acc.w += v0 * s0.w;
            acc.x += v1 * s1.x; acc.y += v1 * s1.y; acc.z += v1 * s1.z; acc.w += v1 * s1.w;
        }
        if (e < e1) {
            int c0 = ecol[e]; float v0 = eval_[e];
            float4 s0 = *reinterpret_cast<const float4*>(support + (size_t)c0 * D + c4);
            acc.x += v0 * s0.x; acc.y += v0 * s0.y; acc.z += v0 * s0.z; acc.w += v0 * s0.w;
        }
        *reinterpret_cast<float4*>(out + (size_t)row * D + c4) = acc;
        sum.x += acc.x; sum.y += acc.y; sum.z += acc.z; sum.w += acc.w;
        sq.x += acc.x * acc.x; sq.y += acc.y * acc.y; sq.z += acc.z * acc.z; sq.w += acc.w * acc.w;
    }

    __shared__ float lsum[D], lsq[D];
    if (tid < D) { lsum[tid] = 0.f; lsq[tid] = 0.f; }
    __syncthreads();
    atomicAdd(&lsum[c4 + 0], sum.x); atomicAdd(&lsum[c4 + 1], sum.y);
    atomicAdd(&lsum[c4 + 2], sum.z); atomicAdd(&lsum[c4 + 3], sum.w);
    atomicAdd(&lsq[c4 + 0], sq.x);  atomicAdd(&lsq[c4 + 1], sq.y);
    atomicAdd(&lsq[c4 + 2], sq.z);  atomicAdd(&lsq[c4 + 3], sq.w);
    __syncthreads();
    if (tid < D) {
        atomicAdd(&colsum[tid], lsum[tid]);
        atomicAdd(&colsq[tid], lsq[tid]);
    }
}

__global__ __launch_bounds__(256) void bn_tanh_kernel(float* __restrict__ out,
                                                      const float* __restrict__ colsum,
                                                      const float* __restrict__ colsq,
                                                      const float* __restrict__ gamma,
                                                      const float* __restrict__ beta) {
    __shared__ float scale[D], shift[D];
    const int tid = threadIdx.x;
    if (tid < D) {
        float mean = colsum[tid] * (1.0f / N_NODES);
        float var  = colsq[tid] * (1.0f / N_NODES) - mean * mean;
        float sc   = rsqrtf(var + BN_EPS) * gamma[tid];
        scale[tid] = sc;
        shift[tid] = beta[tid] - mean * sc;
    }
    __syncthreads();
    const int nq = N_NODES * D / 4;
    for (int q = blockIdx.x * 256 + tid; q < nq; q += gridDim.x * 256) {
        float4 v = reinterpret_cast<float4*>(out)[q];
        int c = (q & 31) * 4;
        v.x = tanhf(v.x * scale[c + 0] + shift[c + 0]);
        v.y = tanhf(v.y * scale[c + 1] + shift[c + 1]);
        v.z = tanhf(v.z * scale[c + 2] + shift[c + 2]);
        v.w = tanhf(v.w * scale[c + 3] + shift[c + 3]);
        reinterpret_cast<float4*>(out)[q] = v;
    }
}

// ---------------- launch ----------------
extern "C" void kernel_launch(void* const* d_in, const int* in_sizes, int n_in,
                              void* d_out, int out_size, void* d_ws, size_t ws_size,
                              hipStream_t stream) {
    const float* input  = (const float*)d_in[0];
    const int*   arow   = (const int*)d_in[1];
    const int*   acol   = (const int*)d_in[2];
    const float* aval   = (const float*)d_in[3];
    const float* weight = (const float*)d_in[4];
    const float* gamma  = (const float*)d_in[5];
    const float* beta   = (const float*)d_in[6];
    float* out = (float*)d_out;

    float* H       = (float*)d_ws;                      // 16384 floats
    float* support = H + D * D;                         // 6.4M floats
    int*   cnt     = (int*)(support + (size_t)N_NODES * D);  // 50000
    int*   rowptr  = cnt + N_NODES;                     // 50001
    int*   rowcur  = rowptr + (N_NODES + 1);            // 50000
    int*   ecol    = rowcur + N_NODES;                  // 800000
    float* eval_   = (float*)(ecol + N_EDGES);          // 800000
    float* colsum  = eval_ + N_EDGES;                   // 128
    // colsq = colsum + 128 (contiguous)

    zero_kernel<<<196, 256, 0, stream>>>(cnt, colsum);
    build_h_kernel<<<64, 256, 0, stream>>>(weight, H);
    count_kernel<<<N_EDGES / 256, 256, 0, stream>>>(arow, cnt);
    scan_kernel<<<1, 1024, 0, stream>>>(cnt, rowptr, rowcur);
    scatter_kernel<<<N_EDGES / 256, 256, 0, stream>>>(arow, acol, aval, rowcur, ecol, eval_);
    gemm_kernel<<<(N_NODES + 31) / 32, 256, 0, stream>>>(input, H, support);
    spmm_kernel<<<2048, 256, 0, stream>>>(support, rowptr, ecol, eval_, out, colsum, colsum + D);
    bn_tanh_kernel<<<2048, 256, 0, stream>>>(out, colsum, colsum + D, gamma, beta);
}

// Round 2
// 257.521 us; speedup vs baseline: 1.1351x; 1.1351x over previous
//
#include <hip/hip_runtime.h>
#include <hip/hip_fp16.h>
#include <math.h>

#define N_NODES 50000
#define N_EDGES 800000
#define D 128
#define BN_EPS 1e-5f

// ---------------- octonion Hamilton tables ----------------
// _OCT_TABLE[j][i] = (component, sign): H[i*16+k][j*16+m] = s * W[k][c*16+m]
__device__ __constant__ int OCT_C[8][8] = {
    {0,1,2,3,4,5,6,7},
    {1,0,3,2,5,4,7,6},
    {2,3,0,1,6,7,4,5},
    {3,2,1,0,7,6,5,4},
    {4,5,6,7,0,1,2,3},
    {5,4,7,6,1,0,3,2},
    {6,7,4,5,2,3,0,1},
    {7,6,5,4,3,2,1,0}};
__device__ __constant__ float OCT_S[8][8] = {
    { 1,-1,-1,-1,-1,-1,-1,-1},
    { 1, 1,-1, 1,-1, 1, 1,-1},
    { 1, 1, 1,-1,-1,-1, 1, 1},
    { 1,-1, 1, 1,-1, 1,-1, 1},
    { 1, 1, 1, 1, 1,-1,-1,-1},
    { 1,-1, 1,-1, 1, 1, 1,-1},
    { 1,-1,-1, 1, 1,-1, 1, 1},
    { 1, 1,-1,-1, 1, 1,-1, 1}};

// ---------------- kernels ----------------

__global__ void zero_kernel(int* __restrict__ cnt, float* __restrict__ stats) {
    int i = blockIdx.x * 256 + threadIdx.x;
    if (i < N_NODES) cnt[i] = 0;
    if (i < 2 * D) stats[i] = 0.0f;
}

__global__ void build_h_kernel(const float* __restrict__ W, float* __restrict__ H) {
    int idx = blockIdx.x * 256 + threadIdx.x;   // 64 blocks * 256 = 16384
    int row = idx >> 7, col = idx & 127;
    int i = row >> 4, k = row & 15, j = col >> 4, m = col & 15;
    int c = OCT_C[j][i];
    float s = OCT_S[j][i];
    H[idx] = s * W[k * D + c * 16 + m];
}

__global__ void count_kernel(const int* __restrict__ arow, int* __restrict__ cnt) {
    int i = blockIdx.x * 256 + threadIdx.x;
    if (i < N_EDGES) atomicAdd(&cnt[arow[i]], 1);
}

// single-block exclusive scan of cnt[0..N_NODES) -> rowptr, rowcur
__global__ void scan_kernel(const int* __restrict__ cnt, int* __restrict__ rowptr,
                            int* __restrict__ rowcur) {
    const int tid = threadIdx.x;        // 1024 threads
    const int lane = tid & 63, wid = tid >> 6;  // 16 waves
    __shared__ int wtot[16];
    __shared__ int carry;
    if (tid == 0) carry = 0;
    __syncthreads();
    const int PER = 8;
    for (int start = 0; start < N_NODES; start += 1024 * PER) {
        int base_i = start + tid * PER;
        int v[PER];
        int s = 0;
#pragma unroll
        for (int j = 0; j < PER; ++j) {
            int i = base_i + j;
            v[j] = (i < N_NODES) ? cnt[i] : 0;
            s += v[j];
        }
        int incl = s;
#pragma unroll
        for (int off = 1; off < 64; off <<= 1) {
            int t = __shfl_up(incl, off, 64);
            if (lane >= off) incl += t;
        }
        if (lane == 63) wtot[wid] = incl;
        __syncthreads();
        if (tid == 0) {
            int acc = carry;
#pragma unroll
            for (int w = 0; w < 16; ++w) { int t = wtot[w]; wtot[w] = acc; acc += t; }
            carry = acc;
        }
        __syncthreads();
        int excl = wtot[wid] + (incl - s);
#pragma unroll
        for (int j = 0; j < PER; ++j) {
            int i = base_i + j;
            if (i < N_NODES) { rowptr[i] = excl; rowcur[i] = excl; }
            excl += v[j];
        }
        __syncthreads();
    }
    if (tid == 0) rowptr[N_NODES] = carry;
}

__global__ void scatter_kernel(const int* __restrict__ arow, const int* __restrict__ acol,
                               const float* __restrict__ aval, int* __restrict__ rowcur,
                               uint2* __restrict__ edata) {
    int i = blockIdx.x * 256 + threadIdx.x;
    if (i < N_EDGES) {
        int r = arow[i];
        int pos = atomicAdd(&rowcur[r], 1);
        edata[pos] = make_uint2((unsigned)acol[i], __float_as_uint(aval[i]));
    }
}

// support = input @ H (fp16 out); H staged in LDS; 32 rows/block
__global__ __launch_bounds__(256) void gemm_kernel(const float* __restrict__ in,
                                                   const float* __restrict__ H,
                                                   __half* __restrict__ support) {
    __shared__ float Hs[D * D];       // 64 KB
    const int tid = threadIdx.x;
    for (int t = tid; t < D * D / 4; t += 256)
        reinterpret_cast<float4*>(Hs)[t] = reinterpret_cast<const float4*>(H)[t];
    __syncthreads();

    const int cq = tid & 31;          // column quad 0..31 -> cols cq*4..cq*4+3
    const int g  = tid >> 5;          // row group 0..7
    const int row0 = blockIdx.x * 32 + g;   // rows row0 + {0,8,16,24}

    const float* ip[4];
    int rows[4];
    float4 acc[4];
#pragma unroll
    for (int r = 0; r < 4; ++r) {
        rows[r] = row0 + r * 8;
        int lr = rows[r] < N_NODES ? rows[r] : N_NODES - 1;
        ip[r] = in + (size_t)lr * D;
        acc[r] = make_float4(0.f, 0.f, 0.f, 0.f);
    }

    for (int kk = 0; kk < D; kk += 4) {
        float4 a[4];
#pragma unroll
        for (int r = 0; r < 4; ++r)
            a[r] = *reinterpret_cast<const float4*>(ip[r] + kk);
#pragma unroll
        for (int j = 0; j < 4; ++j) {
            float4 h = *reinterpret_cast<const float4*>(&Hs[(kk + j) * D + cq * 4]);
#pragma unroll
            for (int r = 0; r < 4; ++r) {
                float aj = (j == 0) ? a[r].x : (j == 1) ? a[r].y : (j == 2) ? a[r].z : a[r].w;
                acc[r].x += aj * h.x;
                acc[r].y += aj * h.y;
                acc[r].z += aj * h.z;
                acc[r].w += aj * h.w;
            }
        }
    }
#pragma unroll
    for (int r = 0; r < 4; ++r)
        if (rows[r] < N_NODES) {
            union { __half2 h[2]; uint2 u; } pk;
            pk.h[0] = __float22half2_rn(make_float2(acc[r].x, acc[r].y));
            pk.h[1] = __float22half2_rn(make_float2(acc[r].z, acc[r].w));
            *reinterpret_cast<uint2*>(support + (size_t)rows[r] * D + cq * 4) = pk.u;
        }
}

// CSR spmm: one 64-lane wave per row, half2 per lane; fused BN column stats
__global__ __launch_bounds__(256) void spmm_kernel(const __half* __restrict__ support,
                                                   const int* __restrict__ rowptr,
                                                   const uint2* __restrict__ edata,
                                                   float* __restrict__ out,
                                                   float* __restrict__ colsum,
                                                   float* __restrict__ colsq) {
    const int tid = threadIdx.x;
    const int lane = tid & 63;
    const int wv = tid >> 6;          // 0..3 waves per block
    const int c2 = lane * 2;

    float s0 = 0.f, s1 = 0.f, q0 = 0.f, q1 = 0.f;

    for (int row = blockIdx.x * 4 + wv; row < N_NODES; row += gridDim.x * 4) {
        float a0 = 0.f, a1 = 0.f;
        const int e1 = rowptr[row + 1];
        int e = rowptr[row];
        for (; e + 4 <= e1; e += 4) {
            uint2 d0 = edata[e + 0], d1 = edata[e + 1], d2 = edata[e + 2], d3 = edata[e + 3];
            float2 f0 = __half22float2(*reinterpret_cast<const __half2*>(support + (size_t)d0.x * D + c2));
            float2 f1 = __half22float2(*reinterpret_cast<const __half2*>(support + (size_t)d1.x * D + c2));
            float2 f2 = __half22float2(*reinterpret_cast<const __half2*>(support + (size_t)d2.x * D + c2));
            float2 f3 = __half22float2(*reinterpret_cast<const __half2*>(support + (size_t)d3.x * D + c2));
            float v0 = __uint_as_float(d0.y), v1 = __uint_as_float(d1.y);
            float v2 = __uint_as_float(d2.y), v3 = __uint_as_float(d3.y);
            a0 += v0 * f0.x; a1 += v0 * f0.y;
            a0 += v1 * f1.x; a1 += v1 * f1.y;
            a0 += v2 * f2.x; a1 += v2 * f2.y;
            a0 += v3 * f3.x; a1 += v3 * f3.y;
        }
        for (; e < e1; ++e) {
            uint2 d0 = edata[e];
            float2 f0 = __half22float2(*reinterpret_cast<const __half2*>(support + (size_t)d0.x * D + c2));
            float v0 = __uint_as_float(d0.y);
            a0 += v0 * f0.x; a1 += v0 * f0.y;
        }
        *reinterpret_cast<float2*>(out + (size_t)row * D + c2) = make_float2(a0, a1);
        s0 += a0; s1 += a1;
        q0 += a0 * a0; q1 += a1 * a1;
    }

    __shared__ float lsum[D], lsq[D];
    if (tid < D) { lsum[tid] = 0.f; lsq[tid] = 0.f; }
    __syncthreads();
    atomicAdd(&lsum[c2 + 0], s0); atomicAdd(&lsum[c2 + 1], s1);
    atomicAdd(&lsq[c2 + 0], q0);  atomicAdd(&lsq[c2 + 1], q1);
    __syncthreads();
    if (tid < D) {
        atomicAdd(&colsum[tid], lsum[tid]);
        atomicAdd(&colsq[tid], lsq[tid]);
    }
}

__global__ __launch_bounds__(256) void bn_tanh_kernel(float* __restrict__ out,
                                                      const float* __restrict__ colsum,
                                                      const float* __restrict__ colsq,
                                                      const float* __restrict__ gamma,
                                                      const float* __restrict__ beta) {
    __shared__ float scale[D], shift[D];
    const int tid = threadIdx.x;
    if (tid < D) {
        float mean = colsum[tid] * (1.0f / N_NODES);
        float var  = colsq[tid] * (1.0f / N_NODES) - mean * mean;
        float sc   = rsqrtf(var + BN_EPS) * gamma[tid];
        scale[tid] = sc;
        shift[tid] = beta[tid] - mean * sc;
    }
    __syncthreads();
    const int nq = N_NODES * D / 4;
    for (int q = blockIdx.x * 256 + tid; q < nq; q += gridDim.x * 256) {
        float4 v = reinterpret_cast<float4*>(out)[q];
        int c = (q & 31) * 4;
        v.x = tanhf(v.x * scale[c + 0] + shift[c + 0]);
        v.y = tanhf(v.y * scale[c + 1] + shift[c + 1]);
        v.z = tanhf(v.z * scale[c + 2] + shift[c + 2]);
        v.w = tanhf(v.w * scale[c + 3] + shift[c + 3]);
        reinterpret_cast<float4*>(out)[q] = v;
    }
}

// ---------------- launch ----------------
extern "C" void kernel_launch(void* const* d_in, const int* in_sizes, int n_in,
                              void* d_out, int out_size, void* d_ws, size_t ws_size,
                              hipStream_t stream) {
    const float* input  = (const float*)d_in[0];
    const int*   arow   = (const int*)d_in[1];
    const int*   acol   = (const int*)d_in[2];
    const float* aval   = (const float*)d_in[3];
    const float* weight = (const float*)d_in[4];
    const float* gamma  = (const float*)d_in[5];
    const float* beta   = (const float*)d_in[6];
    float* out = (float*)d_out;

    float*  H       = (float*)d_ws;                         // 16384 f (64 KB)
    __half* support = (__half*)(H + D * D);                 // 6.4M halfs (12.8 MB)
    uint2*  edata   = (uint2*)(support + (size_t)N_NODES * D);  // 800000 * 8 B
    int*    cnt     = (int*)(edata + N_EDGES);              // 50000
    int*    rowptr  = cnt + N_NODES;                        // 50001
    int*    rowcur  = rowptr + (N_NODES + 1);               // 50000
    float*  colsum  = (float*)(rowcur + N_NODES);           // 128
    // colsq = colsum + 128 (contiguous)

    zero_kernel<<<196, 256, 0, stream>>>(cnt, colsum);
    build_h_kernel<<<64, 256, 0, stream>>>(weight, H);
    count_kernel<<<N_EDGES / 256, 256, 0, stream>>>(arow, cnt);
    scan_kernel<<<1, 1024, 0, stream>>>(cnt, rowptr, rowcur);
    scatter_kernel<<<N_EDGES / 256, 256, 0, stream>>>(arow, acol, aval, rowcur, edata);
    gemm_kernel<<<(N_NODES + 31) / 32, 256, 0, stream>>>(input, H, support);
    spmm_kernel<<<2048, 256, 0, stream>>>(support, rowptr, edata, out, colsum, colsum + D);
    bn_tanh_kernel<<<2048, 256, 0, stream>>>(out, colsum, colsum + D, gamma, beta);
}